// Round 6
// baseline (190.984 us; speedup 1.0000x reference)
//
#include <hip/hip_runtime.h>

#define N_NODES 50000
#define N_EDGES 800000
#define IN_DIM 128
#define OUT_DIM 64
#define PAD 64          // bucket capacity; P(deg>64 | Poisson(16)) ~ 1e-19
#define NPART 6250      // N_NODES / 8 partitions (one per XCD)
#define FCHUNK 2048     // edges per claimed fill chunk
#define NCHUNK ((N_EDGES + FCHUNK - 1) / FCHUNK)   // 391
#define WAVG_BLOCKS 32
#define FILL_BLOCKS 2048

typedef __attribute__((ext_vector_type(8))) short bf16x8;
typedef __attribute__((ext_vector_type(4))) float f32x4;

__device__ inline unsigned short f2bf(float x) {
    unsigned u = __builtin_bit_cast(unsigned, x);
    unsigned r = (u + 0x7FFFu + ((u >> 16) & 1u)) >> 16;
    return (unsigned short)r;
}

// ---------------------------------------------------------------------------
// K1 (fused): blocks [0,32) -> wT[f][d] = bf16(mean_k W[k][d][f]).
// blocks [32,..) -> XCD-verified fill: read the block's PHYSICAL XCD via
// s_getreg(HW_REG_XCC_ID=20) [m09], then claim edge chunks from that XCD's
// private cursor.  All writers of a given cnt/esrc line are therefore
// physically on one XCD -> stores merge to full lines in its L2 (kills the
// 44 MB partial-line write-through seen in R4).  Correct for ANY block->XCD
// mapping: each (chunk, partition) pair is processed exactly once.
// ---------------------------------------------------------------------------
__global__ __launch_bounds__(256) void wf_kernel(const float* __restrict__ W,
                                                 unsigned short* __restrict__ wT,
                                                 const int* __restrict__ src,
                                                 const int* __restrict__ dst,
                                                 int* __restrict__ cnt,
                                                 int* __restrict__ cursor8,
                                                 unsigned short* __restrict__ esrc) {
    if (blockIdx.x < WAVG_BLOCKS) {
        const int i = blockIdx.x * 256 + threadIdx.x;   // 0..8191
        const int f = i >> 7, d = i & 127;
        float s = W[d * 64 + f] + W[8192 + d * 64 + f] +
                  W[16384 + d * 64 + f] + W[24576 + d * 64 + f];
        wT[i] = f2bf(0.25f * s);
        return;
    }

    int xcc;
    asm volatile("s_getreg_b32 %0, hwreg(20)" : "=s"(xcc));  // HW_REG_XCC_ID
    xcc &= 7;
    const int lo = xcc * NPART;
    const int hi = lo + NPART;

    __shared__ int s_chunk;
    for (;;) {
        if (threadIdx.x == 0) s_chunk = atomicAdd(&cursor8[xcc], 1);
        __syncthreads();
        const int chunk = s_chunk;
        __syncthreads();
        if (chunk >= NCHUNK) break;
        const int e0 = chunk * FCHUNK;
        const int e1 = (e0 + FCHUNK < N_EDGES) ? e0 + FCHUNK : N_EDGES;
        for (int e = e0 + (int)threadIdx.x; e < e1; e += 256) {
            const int d = dst[e];
            const int s = src[e];          // unconditional coalesced load
            if (d >= lo && d < hi) {
                int pos = atomicAdd(&cnt[d], 1);
                if (pos < PAD) esrc[(size_t)d * PAD + pos] = (unsigned short)s;
            }
        }
    }
}

// ---------------------------------------------------------------------------
// K2: hp = h @ wavg via mfma_f32_16x16x32_bf16, split column-wise:
// hp0[n][0..32) = cols 0..31, hp1[n][0..32) = cols 32..63  (bf16).
// One wave per 16 nodes; B (wT) in 64 VGPRs; A from global with in-reg cvt.
// ---------------------------------------------------------------------------
__global__ __launch_bounds__(256) void gemm_mfma_kernel(const float* __restrict__ h,
                                                        const unsigned short* __restrict__ wT,
                                                        unsigned short* __restrict__ hp0,
                                                        unsigned short* __restrict__ hp1) {
    const int wave = (blockIdx.x << 2) + (threadIdx.x >> 6);
    const int n0 = wave << 4;
    if (n0 >= N_NODES) return;
    const int lane = threadIdx.x & 63;
    const int lm = lane & 15;
    const int lg = lane >> 4;

    bf16x8 bfrag[4][4];
#pragma unroll
    for (int nt = 0; nt < 4; ++nt)
#pragma unroll
        for (int ks = 0; ks < 4; ++ks)
            bfrag[nt][ks] = *(const bf16x8*)&wT[(nt * 16 + lm) * 128 + ks * 32 + lg * 8];

    f32x4 acc[4];
#pragma unroll
    for (int nt = 0; nt < 4; ++nt) acc[nt] = (f32x4)0.0f;

    const float* hrow = h + (size_t)(n0 + lm) * IN_DIM;
#pragma unroll
    for (int ks = 0; ks < 4; ++ks) {
        const float4 a0 = *(const float4*)&hrow[ks * 32 + lg * 8];
        const float4 a1 = *(const float4*)&hrow[ks * 32 + lg * 8 + 4];
        bf16x8 af;
        af[0] = (short)f2bf(a0.x); af[1] = (short)f2bf(a0.y);
        af[2] = (short)f2bf(a0.z); af[3] = (short)f2bf(a0.w);
        af[4] = (short)f2bf(a1.x); af[5] = (short)f2bf(a1.y);
        af[6] = (short)f2bf(a1.z); af[7] = (short)f2bf(a1.w);
#pragma unroll
        for (int nt = 0; nt < 4; ++nt)
            acc[nt] = __builtin_amdgcn_mfma_f32_16x16x32_bf16(af, bfrag[nt][ks], acc[nt], 0, 0, 0);
    }

#pragma unroll
    for (int nt = 0; nt < 4; ++nt)
#pragma unroll
        for (int r = 0; r < 4; ++r) {
            const int m = lg * 4 + r;
            unsigned short val = f2bf(acc[nt][r]);
            if (nt < 2) hp0[(size_t)(n0 + m) * 32 + nt * 16 + lm] = val;
            else        hp1[(size_t)(n0 + m) * 32 + (nt - 2) * 16 + lm] = val;
        }
}

// ---------------------------------------------------------------------------
// K3 (x2): gather-sum + bias + relu over ONE 32-col half.  The half's hp
// array is 3.2 MB < 4 MB -> L2-RESIDENT in every XCD -> row gathers served
// at L2 bandwidth instead of L3 latency.  16-lane groups, 4 nodes/wave;
// lane = uint (2 bf16 cols); 16-deep load batches pinned by sched_barrier.
// ---------------------------------------------------------------------------
__global__ __launch_bounds__(256) void gather_kernel(const unsigned* __restrict__ hph,
                                                     const unsigned short* __restrict__ esrc,
                                                     const int* __restrict__ cnt,
                                                     const float* __restrict__ bias,
                                                     float* __restrict__ out,
                                                     int half) {
    const int n = blockIdx.x * 16 + (threadIdx.x >> 4);
    const int l = threadIdx.x & 15;
    if (n >= N_NODES) return;

    int deg = cnt[n];
    deg = deg > PAD ? PAD : deg;

    // lane l holds bucket slots 4l..4l+3: sv.x = {4l,4l+1}, sv.y = {4l+2,4l+3}
    const uint2 sv = ((const uint2*)(esrc + (size_t)n * PAD))[l];

    float a0 = 0.f, a1 = 0.f;

    for (int j0 = 0; j0 < deg; j0 += 16) {
        const int m = deg - j0;
        const int b = j0 >> 2;
        unsigned v[16];
#pragma unroll
        for (int k = 0; k < 16; ++k) {
            unsigned w = __shfl(((k >> 1) & 1) ? sv.y : sv.x, b + (k >> 2), 16);
            unsigned sid = (k & 1) ? (w >> 16) : (w & 0xFFFFu);
            v[k] = hph[((size_t)sid << 4) + l];   // 64B row per 16-lane group
        }
        __builtin_amdgcn_sched_barrier(0);        // keep all 16 loads in flight
#pragma unroll
        for (int k = 0; k < 16; ++k) {
            if (k < m) {
                a0 += __builtin_bit_cast(float, v[k] << 16);
                a1 += __builtin_bit_cast(float, v[k] & 0xFFFF0000u);
            }
        }
    }

    const float2 bv = ((const float2*)bias)[(half << 4) + l];
    float2 o;
    o.x = fmaxf(a0 + bv.x, 0.f);
    o.y = fmaxf(a1 + bv.y, 0.f);
    ((float2*)out)[(size_t)n * 32 + (half << 4) + l] = o;
}

extern "C" void kernel_launch(void* const* d_in, const int* in_sizes, int n_in,
                              void* d_out, int out_size, void* d_ws, size_t ws_size,
                              hipStream_t stream) {
    const float* h   = (const float*)d_in[0];
    const float* W   = (const float*)d_in[1];
    const float* b   = (const float*)d_in[2];
    const int*   src = (const int*)d_in[3];
    const int*   dst = (const int*)d_in[4];
    float* out = (float*)d_out;

    // ws layout (bytes):
    //   [0, 32K)        wT      (64*128 bf16)
    //   [+3.2M)         hp0     (50000*32 bf16, cols  0..31)
    //   [+3.2M)         hp1     (50000*32 bf16, cols 32..63)
    //   cnt[50000] + cursor8[8] ints  (memset 0 together)
    //   esrc[50000*64] ushort buckets
    char* p = (char*)d_ws;
    unsigned short* wT  = (unsigned short*)p;   p += 32 * 1024;
    unsigned short* hp0 = (unsigned short*)p;   p += (size_t)N_NODES * 32 * 2;
    unsigned short* hp1 = (unsigned short*)p;   p += (size_t)N_NODES * 32 * 2;
    int* cnt = (int*)p;                         p += (size_t)(N_NODES + 8) * 4;
    int* cursor8 = cnt + N_NODES;
    unsigned short* esrc = (unsigned short*)p;

    hipMemsetAsync(cnt, 0, (size_t)(N_NODES + 8) * 4, stream);

    wf_kernel<<<WAVG_BLOCKS + FILL_BLOCKS, 256, 0, stream>>>(W, wT, src, dst, cnt, cursor8, esrc);
    gemm_mfma_kernel<<<(N_NODES / 16 + 3) / 4, 256, 0, stream>>>(h, wT, hp0, hp1);
    gather_kernel<<<(N_NODES + 15) / 16, 256, 0, stream>>>((const unsigned*)hp0, esrc, cnt, b, out, 0);
    gather_kernel<<<(N_NODES + 15) / 16, 256, 0, stream>>>((const unsigned*)hp1, esrc, cnt, b, out, 1);
}

// Round 7
// 136.435 us; speedup vs baseline: 1.3998x; 1.3998x over previous
//
#include <hip/hip_runtime.h>

#define N_NODES 50000
#define N_EDGES 800000
#define IN_DIM 128
#define OUT_DIM 64
#define PAD 64          // bucket capacity; P(deg>64 | Poisson(16)) ~ 1e-19
#define BINS 196        // bin = dst >> 8  (256 nodes per bin)
#define BCAP 5120       // scratch slots per bin (mean 4082, +16 sd)
#define FCHUNK 2048
#define NCHUNK ((N_EDGES + FCHUNK - 1) / FCHUNK)   // 391
#define WAVG_BLOCKS 32

typedef __attribute__((ext_vector_type(8))) short bf16x8;
typedef __attribute__((ext_vector_type(4))) float f32x4;

__device__ inline unsigned short f2bf(float x) {
    unsigned u = __builtin_bit_cast(unsigned, x);
    unsigned r = (u + 0x7FFFu + ((u >> 16) & 1u)) >> 16;
    return (unsigned short)r;
}

// ---------------------------------------------------------------------------
// K1: blocks [0,32) -> wT[f][d] = bf16(mean_k W[k][d][f]).
// blocks [32,..)  -> PASS A of the CSR bin-sort: per-block LDS histogram of
// dst>>8 (196 bins), one global atomic per (block,bin) to reserve scratch
// space, then scatter packed (dstlow<<16 | src) into per-bin regions.
// Replaces 800k random partial-line bucket writes (the 13 G-lines/s wall
// measured in R4/R6) with ~77k block-contiguous appends.
// ---------------------------------------------------------------------------
__global__ __launch_bounds__(256) void binscat_kernel(const float* __restrict__ W,
                                                      unsigned short* __restrict__ wT,
                                                      const int* __restrict__ src,
                                                      const int* __restrict__ dst,
                                                      int* __restrict__ binCursor,
                                                      unsigned* __restrict__ scratch) {
    if (blockIdx.x < WAVG_BLOCKS) {
        const int i = blockIdx.x * 256 + threadIdx.x;   // 0..8191
        const int f = i >> 7, d = i & 127;
        float s = W[d * 64 + f] + W[8192 + d * 64 + f] +
                  W[16384 + d * 64 + f] + W[24576 + d * 64 + f];
        wT[i] = f2bf(0.25f * s);
        return;
    }
    const int blk = blockIdx.x - WAVG_BLOCKS;          // 0..390
    const int e0 = blk * FCHUNK;
    const int e1 = (e0 + FCHUNK < N_EDGES) ? e0 + FCHUNK : N_EDGES;

    __shared__ int hist[BINS];
    __shared__ int base[BINS];
    for (int i = threadIdx.x; i < BINS; i += 256) hist[i] = 0;
    __syncthreads();
    for (int e = e0 + (int)threadIdx.x; e < e1; e += 256)
        atomicAdd(&hist[dst[e] >> 8], 1);
    __syncthreads();
    for (int i = threadIdx.x; i < BINS; i += 256)
        base[i] = atomicAdd(&binCursor[i], hist[i]);   // global reservation
    __syncthreads();
    for (int e = e0 + (int)threadIdx.x; e < e1; e += 256) {
        const int d = dst[e];
        const int bin = d >> 8;
        const int pos = atomicAdd(&base[bin], 1);      // LDS bump -> global slot
        if (pos < BCAP)
            scratch[(size_t)bin * BCAP + pos] =
                ((unsigned)(d & 255) << 16) | (unsigned)src[e];
    }
}

// ---------------------------------------------------------------------------
// K2: PASS B — one block per bin.  Build the bin's 256 node-buckets in LDS
// (LDS atomics only), then stream buckets (32 KB contiguous uint4) and cnt
// to global.  All global writes are full-line sequential.
// ---------------------------------------------------------------------------
__global__ __launch_bounds__(256) void bucket_kernel(const unsigned* __restrict__ scratch,
                                                     const int* __restrict__ binCursor,
                                                     int* __restrict__ cnt,
                                                     unsigned short* __restrict__ esrc) {
    const int b = blockIdx.x;                 // 0..195
    __shared__ unsigned short buck[256 * PAD];  // 32 KB
    __shared__ int lcnt[256];
    lcnt[threadIdx.x] = 0;
    __syncthreads();

    int ne = binCursor[b];
    if (ne > BCAP) ne = BCAP;
    const unsigned* sp = scratch + (size_t)b * BCAP;
    for (int i = threadIdx.x; i < ne; i += 256) {
        const unsigned pk = sp[i];
        const int dl = pk >> 16;
        const int pos = atomicAdd(&lcnt[dl], 1);
        if (pos < PAD) buck[dl * PAD + pos] = (unsigned short)(pk & 0xFFFFu);
    }
    __syncthreads();

    const int n0 = b << 8;
    if (n0 + (int)threadIdx.x < N_NODES) cnt[n0 + threadIdx.x] = lcnt[threadIdx.x];
    int nvalid = N_NODES - n0;
    if (nvalid > 256) nvalid = 256;
    uint4* eg = (uint4*)(esrc + (size_t)n0 * PAD);
    const uint4* bl = (const uint4*)buck;
    for (int i = threadIdx.x; i < nvalid * 8; i += 256) eg[i] = bl[i];  // 128B/node
}

// ---------------------------------------------------------------------------
// K3: hp = h @ wavg via mfma_f32_16x16x32_bf16, split column-wise:
// hp0 = cols 0..31, hp1 = cols 32..63 (bf16, 3.2 MB each -> L2-resident).
// ---------------------------------------------------------------------------
__global__ __launch_bounds__(256) void gemm_mfma_kernel(const float* __restrict__ h,
                                                        const unsigned short* __restrict__ wT,
                                                        unsigned short* __restrict__ hp0,
                                                        unsigned short* __restrict__ hp1) {
    const int wave = (blockIdx.x << 2) + (threadIdx.x >> 6);
    const int n0 = wave << 4;
    if (n0 >= N_NODES) return;
    const int lane = threadIdx.x & 63;
    const int lm = lane & 15;
    const int lg = lane >> 4;

    bf16x8 bfrag[4][4];
#pragma unroll
    for (int nt = 0; nt < 4; ++nt)
#pragma unroll
        for (int ks = 0; ks < 4; ++ks)
            bfrag[nt][ks] = *(const bf16x8*)&wT[(nt * 16 + lm) * 128 + ks * 32 + lg * 8];

    f32x4 acc[4];
#pragma unroll
    for (int nt = 0; nt < 4; ++nt) acc[nt] = (f32x4)0.0f;

    const float* hrow = h + (size_t)(n0 + lm) * IN_DIM;
#pragma unroll
    for (int ks = 0; ks < 4; ++ks) {
        const float4 a0 = *(const float4*)&hrow[ks * 32 + lg * 8];
        const float4 a1 = *(const float4*)&hrow[ks * 32 + lg * 8 + 4];
        bf16x8 af;
        af[0] = (short)f2bf(a0.x); af[1] = (short)f2bf(a0.y);
        af[2] = (short)f2bf(a0.z); af[3] = (short)f2bf(a0.w);
        af[4] = (short)f2bf(a1.x); af[5] = (short)f2bf(a1.y);
        af[6] = (short)f2bf(a1.z); af[7] = (short)f2bf(a1.w);
#pragma unroll
        for (int nt = 0; nt < 4; ++nt)
            acc[nt] = __builtin_amdgcn_mfma_f32_16x16x32_bf16(af, bfrag[nt][ks], acc[nt], 0, 0, 0);
    }

#pragma unroll
    for (int nt = 0; nt < 4; ++nt)
#pragma unroll
        for (int r = 0; r < 4; ++r) {
            const int m = lg * 4 + r;
            unsigned short val = f2bf(acc[nt][r]);
            if (nt < 2) hp0[(size_t)(n0 + m) * 32 + nt * 16 + lm] = val;
            else        hp1[(size_t)(n0 + m) * 32 + (nt - 2) * 16 + lm] = val;
        }
}

// ---------------------------------------------------------------------------
// K4 (x2): gather-sum + bias + relu over one 32-col half (3.2 MB,
// L2-resident in every XCD).  16-lane groups, 4 nodes/wave; 16-deep load
// batches pinned in flight by sched_barrier(0).
// ---------------------------------------------------------------------------
__global__ __launch_bounds__(256) void gather_kernel(const unsigned* __restrict__ hph,
                                                     const unsigned short* __restrict__ esrc,
                                                     const int* __restrict__ cnt,
                                                     const float* __restrict__ bias,
                                                     float* __restrict__ out,
                                                     int half) {
    const int n = blockIdx.x * 16 + (threadIdx.x >> 4);
    const int l = threadIdx.x & 15;
    if (n >= N_NODES) return;

    int deg = cnt[n];
    deg = deg > PAD ? PAD : deg;

    const uint2 sv = ((const uint2*)(esrc + (size_t)n * PAD))[l];

    float a0 = 0.f, a1 = 0.f;

    for (int j0 = 0; j0 < deg; j0 += 16) {
        const int m = deg - j0;
        const int b = j0 >> 2;
        unsigned v[16];
#pragma unroll
        for (int k = 0; k < 16; ++k) {
            unsigned w = __shfl(((k >> 1) & 1) ? sv.y : sv.x, b + (k >> 2), 16);
            unsigned sid = (k & 1) ? (w >> 16) : (w & 0xFFFFu);
            v[k] = hph[((size_t)sid << 4) + l];   // 64B full line per group
        }
        __builtin_amdgcn_sched_barrier(0);
#pragma unroll
        for (int k = 0; k < 16; ++k) {
            if (k < m) {
                a0 += __builtin_bit_cast(float, v[k] << 16);
                a1 += __builtin_bit_cast(float, v[k] & 0xFFFF0000u);
            }
        }
    }

    const float2 bv = ((const float2*)bias)[(half << 4) + l];
    float2 o;
    o.x = fmaxf(a0 + bv.x, 0.f);
    o.y = fmaxf(a1 + bv.y, 0.f);
    ((float2*)out)[(size_t)n * 32 + (half << 4) + l] = o;
}

extern "C" void kernel_launch(void* const* d_in, const int* in_sizes, int n_in,
                              void* d_out, int out_size, void* d_ws, size_t ws_size,
                              hipStream_t stream) {
    const float* h   = (const float*)d_in[0];
    const float* W   = (const float*)d_in[1];
    const float* b   = (const float*)d_in[2];
    const int*   src = (const int*)d_in[3];
    const int*   dst = (const int*)d_in[4];
    float* out = (float*)d_out;

    // ws layout (bytes):
    //   [0, 32K)   wT (64*128 bf16)
    //   [+3.2M)    hp0   [+3.2M) hp1
    //   cnt[50000] ints          (written by bucket_kernel, no memset needed)
    //   binCursor[196] ints      (memset 0)
    //   esrc[50000*64] ushort
    //   scratch[196*5120] uint
    char* p = (char*)d_ws;
    unsigned short* wT  = (unsigned short*)p;   p += 32 * 1024;
    unsigned short* hp0 = (unsigned short*)p;   p += (size_t)N_NODES * 32 * 2;
    unsigned short* hp1 = (unsigned short*)p;   p += (size_t)N_NODES * 32 * 2;
    int* cnt = (int*)p;                         p += (size_t)N_NODES * 4;
    int* binCursor = (int*)p;                   p += (size_t)BINS * 4;
    unsigned short* esrc = (unsigned short*)p;  p += (size_t)N_NODES * PAD * 2;
    unsigned* scratch = (unsigned*)p;

    hipMemsetAsync(binCursor, 0, (size_t)BINS * 4, stream);

    binscat_kernel<<<WAVG_BLOCKS + NCHUNK, 256, 0, stream>>>(W, wT, src, dst, binCursor, scratch);
    bucket_kernel<<<BINS, 256, 0, stream>>>(scratch, binCursor, cnt, esrc);
    gemm_mfma_kernel<<<(N_NODES / 16 + 3) / 4, 256, 0, stream>>>(h, wT, hp0, hp1);
    gather_kernel<<<(N_NODES + 15) / 16, 256, 0, stream>>>((const unsigned*)hp0, esrc, cnt, b, out, 0);
    gather_kernel<<<(N_NODES + 15) / 16, 256, 0, stream>>>((const unsigned*)hp1, esrc, cnt, b, out, 1);
}